// Round 3
// baseline (1602.970 us; speedup 1.0000x reference)
//
#include <hip/hip_runtime.h>
#include <stdint.h>

// ---------------- problem constants (fixed by the reference) ----------------
#define N_NODES   8000
#define N_EDGES   128000
#define WALK_LEN  16
#define OUT_DIM   8

// ---------------- main-kernel layout constants ----------------
#define NSLOT     8016                 // 8000 real rows + 16 staggered dummy zero-rows
#define BUF_BYTES (NSLOT * 8)          // 64128 bytes per f16x4 buffer (x2 = 128256 <= 160K)
#define PADCAP    (N_EDGES + 4 * N_NODES)  // 160000: per-col pad-to-4 worst case

typedef _Float16 half2_t __attribute__((ext_vector_type(2)));

// ---------------- K0: init cnt/invdeg ----------------
__global__ void k0_init(uint32_t* __restrict__ cnt, float* __restrict__ invdeg) {
    int i = blockIdx.x * 256 + threadIdx.x;
    if (i < N_NODES) { cnt[i] = 0u; invdeg[i] = 1.0f; }
}

// ---------------- K1: in-degree count + invdeg scatter ----------------
// invdeg[r] = rw[e] for every edge with row r (all identical: 1/deg(r)) — benign race.
// Nodes with no out-edges keep invdeg=1.0, matching the reference's clip(deg,1).
__global__ void k1_count(const int* __restrict__ ei, const float* __restrict__ rw,
                         uint32_t* __restrict__ cnt, float* __restrict__ invdeg) {
    int e = blockIdx.x * 256 + threadIdx.x;
    if (e < N_EDGES) {
        int r = ei[e];
        int c = ei[N_EDGES + e];
        atomicAdd(&cnt[c], 1u);
        invdeg[r] = rw[e];
    }
}

// ---------------- K2: counting sort of columns by in-degree ----------------
// perm[slot] = col, rank[col] = slot.  Sorted order = near-uniform trip counts per wave.
__global__ __launch_bounds__(1024) void k2_sort(const uint32_t* __restrict__ cnt,
                                                uint32_t* __restrict__ perm,
                                                uint32_t* __restrict__ rank) {
    __shared__ uint32_t h[256];
    __shared__ uint32_t hoff[256];
    int t = threadIdx.x;
    if (t < 256) h[t] = 0u;
    __syncthreads();
    for (int i = t; i < N_NODES; i += 1024) {
        uint32_t d = cnt[i]; if (d > 255u) d = 255u;
        atomicAdd(&h[d], 1u);
    }
    __syncthreads();
    if (t == 0) {
        uint32_t run = 0;
        for (int b = 0; b < 256; ++b) { hoff[b] = run; run += h[b]; }
    }
    __syncthreads();
    for (int i = t; i < N_NODES; i += 1024) {
        uint32_t d = cnt[i]; if (d > 255u) d = 255u;
        uint32_t slot = atomicAdd(&hoff[d], 1u);
        perm[slot] = (uint32_t)i;
        rank[i] = slot;
    }
}

// ---------------- K3: exclusive scan of pad-to-4 degrees over perm order ----------------
__global__ __launch_bounds__(1024) void k3_scan(const uint32_t* __restrict__ cnt,
                                                const uint32_t* __restrict__ perm,
                                                uint32_t* __restrict__ poffs,
                                                uint32_t* __restrict__ pcur) {
    __shared__ uint32_t s[2][8192];   // 64 KB, Hillis-Steele double buffer
    int t = threadIdx.x;
    for (int i = t; i < 8192; i += 1024) {
        uint32_t v = 0u;
        if (i < N_NODES) v = (cnt[perm[i]] + 3u) & ~3u;   // pad each column to x4
        s[0][i] = v;
    }
    __syncthreads();
    int src = 0;
    for (int d = 1; d < 8192; d <<= 1) {
        for (int i = t; i < 8192; i += 1024) {
            uint32_t v = s[src][i];
            if (i >= d) v += s[src][i - d];
            s[src ^ 1][i] = v;
        }
        __syncthreads();
        src ^= 1;
    }
    for (int i = t; i < 8192; i += 1024) {
        if (i < N_NODES) {
            uint32_t ex = (i == 0) ? 0u : s[src][i - 1];
            poffs[i] = ex;
            pcur[i]  = ex;
        }
    }
    if (t == 0) poffs[N_NODES] = s[src][N_NODES - 1];
}

// ---------------- K4: scatter edges into permuted CSC, pre-scaled byte offsets ----------------
__global__ void k4_scatter(const int* __restrict__ ei, const uint32_t* __restrict__ rank,
                           uint32_t* __restrict__ pcur, uint16_t* __restrict__ prows) {
    int e = blockIdx.x * 256 + threadIdx.x;
    if (e < N_EDGES) {
        int r = ei[e];
        int c = ei[N_EDGES + e];
        uint32_t slot = rank[c];
        uint32_t pos  = atomicAdd(&pcur[slot], 1u);
        prows[pos] = (uint16_t)(r * 8);   // byte offset of row r in the f16x4 LDS buffer
    }
}

// ---------------- K4b: per-column bank-stagger sort (correctness-neutral reorder) ----
// Sort each column's edges by bank-pair key ((row&15) - rot) & 15, rot = lane/4.
// With degree-sorted wave-uniform trip counts, the wave's 64 lanes then sit at evenly
// staggered bank-pairs every iteration: exactly 4 lanes/pair (1.58x, m136) instead of
// random (~2.9x). Pads go to staggered dummy zero-rows 8000..8015.
__global__ __launch_bounds__(256) void k4b_banksort(const uint32_t* __restrict__ cnt,
                                                    const uint32_t* __restrict__ perm,
                                                    const uint32_t* __restrict__ poffs,
                                                    const uint16_t* __restrict__ prows,
                                                    uint16_t* __restrict__ prows2) {
    __shared__ uint16_t pos[256][16];
    int t = threadIdx.x;
    int i = blockIdx.x * 256 + t;
    if (i >= N_NODES) return;
    uint32_t col  = perm[i];
    uint32_t n    = cnt[col];
    uint32_t base = poffs[i];
    uint32_t end  = poffs[i + 1];
    uint32_t rot  = ((uint32_t)i & 63u) >> 2;   // 0..15, matches k5 lane = (slot%1024)%64

#pragma unroll
    for (int k = 0; k < 16; ++k) pos[t][k] = 0;
    for (uint32_t p = 0; p < n; ++p) {
        uint32_t r = (uint32_t)prows[base + p] >> 3;
        pos[t][((r & 15u) + 16u - rot) & 15u]++;
    }
    uint32_t run = 0;
#pragma unroll
    for (int k = 0; k < 16; ++k) { uint32_t hh = pos[t][k]; pos[t][k] = (uint16_t)run; run += hh; }
    for (uint32_t p = 0; p < n; ++p) {
        uint16_t off = prows[base + p];
        uint32_t k = (((uint32_t)off >> 3) & 15u);
        k = (k + 16u - rot) & 15u;
        prows2[base + pos[t][k]] = off;
        pos[t][k]++;
    }
    uint16_t dummyoff = (uint16_t)((8000u + ((rot + 15u) & 15u)) * 8u);
    for (uint32_t p = base + n; p < end; ++p) prows2[p] = dummyoff;
}

// ---------------- K5: the 16-step walk, 4 columns per block ----------------
// State X~ = 1024 * invdeg ⊙ X kept in f16x4 rows (cols 0..3), double-buffered in LDS.
// step: acc(c) = sum over in-edges of X~[row]  (the rw weight is folded into X~)
//        diag_s = acc/1024 at c == own column;  X~_next[c] = invdeg[c] * acc.
__global__ __launch_bounds__(1024) void k5_walk(const uint32_t* __restrict__ perm,
                                                const uint32_t* __restrict__ poffs,
                                                const uint16_t* __restrict__ prows,
                                                const float* __restrict__ invdeg,
                                                float* __restrict__ diag) {
    __shared__ uint2 Xs[2][NSLOT];   // 128256 bytes static LDS
    const int t  = threadIdx.x;
    const int c0 = blockIdx.x * 4;

    // zero both buffers (dummy rows 8000..8015 must stay zero in both forever)
    for (int i = t; i < NSLOT; i += 1024) {
        Xs[0][i] = make_uint2(0u, 0u);
        Xs[1][i] = make_uint2(0u, 0u);
    }
    __syncthreads();
    if (t < 4) {
        int c = c0 + t;
        float v = invdeg[c] * 1024.0f;   // scaled one-hot, weight pre-folded
        half2_t p0, p1;
        p0.x = (_Float16)(t == 0 ? v : 0.0f);
        p0.y = (_Float16)(t == 1 ? v : 0.0f);
        p1.x = (_Float16)(t == 2 ? v : 0.0f);
        p1.y = (_Float16)(t == 3 ? v : 0.0f);
        uint2 w;
        w.x = __builtin_bit_cast(uint32_t, p0);
        w.y = __builtin_bit_cast(uint32_t, p1);
        Xs[0][c] = w;
    }

    // cache this thread's 8 slots in registers for all 16 steps
    uint32_t sc[8], sb[8], se[8];
    float sid[8];
#pragma unroll
    for (int q = 0; q < 8; ++q) {
        int i = q * 1024 + t;
        if (i < N_NODES) {
            uint32_t c = perm[i];
            sc[q] = c;
            sb[q] = poffs[i];
            se[q] = poffs[i + 1];
            sid[q] = invdeg[c];
        } else {
            sc[q] = 0xFFFFFFFFu; sb[q] = 0u; se[q] = 0u; sid[q] = 0.0f;
        }
    }
    __syncthreads();

    const char* lb = (const char*)&Xs[0][0];

    for (int s = 0; s < WALK_LEN; ++s) {
        const int p = s & 1;
        const char* rbase = lb + p * BUF_BYTES;
        char*       wbase = (char*)lb + (p ^ 1) * BUF_BYTES;

#pragma unroll
        for (int q = 0; q < 8; ++q) {
            if (sc[q] == 0xFFFFFFFFu) continue;
            float a0 = 0.f, a1 = 0.f, a2 = 0.f, a3 = 0.f;
            for (uint32_t e = sb[q]; e < se[q]; e += 4) {
                uint2 cc = *(const uint2*)(prows + e);   // 4 pre-scaled u16 offsets
#define EDGE_AT(OFF)                                                        \
                {   uint2 wv = *(const uint2*)(rbase + (OFF));              \
                    half2_t hA = __builtin_bit_cast(half2_t, wv.x);         \
                    half2_t hB = __builtin_bit_cast(half2_t, wv.y);         \
                    a0 += (float)hA.x;  a1 += (float)hA.y;                  \
                    a2 += (float)hB.x;  a3 += (float)hB.y;                  \
                }
                EDGE_AT(cc.x & 0xFFFFu)  EDGE_AT(cc.x >> 16)
                EDGE_AT(cc.y & 0xFFFFu)  EDGE_AT(cc.y >> 16)
#undef EDGE_AT
            }
            uint32_t c = sc[q];
            uint32_t j = c - (uint32_t)c0;
            if (j < 4u) {   // this column's diagonal entry (undo the x1024 scaling)
                float dv = (j == 0u) ? a0 : (j == 1u) ? a1 : (j == 2u) ? a2 : a3;
                diag[c * WALK_LEN + s] = dv * (1.0f / 1024.0f);
            }
            float id = sid[q];
            half2_t h0, h1;
            h0.x = (_Float16)(a0 * id);   // RNE, no RTZ bias
            h0.y = (_Float16)(a1 * id);
            h1.x = (_Float16)(a2 * id);
            h1.y = (_Float16)(a3 * id);
            uint2 w;
            w.x = __builtin_bit_cast(uint32_t, h0);
            w.y = __builtin_bit_cast(uint32_t, h1);
            *(uint2*)(wbase + c * 8u) = w;
        }
        __syncthreads();
    }
}

// ---------------- K6: linear layer out = diag @ W^T + b ----------------
__global__ void k6_out(const float* __restrict__ diag, const float* __restrict__ W,
                       const float* __restrict__ b, float* __restrict__ out) {
    int i = blockIdx.x * 256 + threadIdx.x;
    if (i < N_NODES * OUT_DIM) {
        int n = i >> 3;
        int d = i & 7;
        float acc = b[d];
#pragma unroll
        for (int k = 0; k < WALK_LEN; ++k)
            acc += diag[n * WALK_LEN + k] * W[d * WALK_LEN + k];
        out[i] = acc;
    }
}

// ---------------- launcher ----------------
extern "C" void kernel_launch(void* const* d_in, const int* in_sizes, int n_in,
                              void* d_out, int out_size, void* d_ws, size_t ws_size,
                              hipStream_t stream) {
    const int*   ei = (const int*)d_in[0];     // [2, E] int32: rows then cols
    const float* rw = (const float*)d_in[2];   // [E] f32
    const float* W  = (const float*)d_in[3];   // [8,16] f32
    const float* b  = (const float*)d_in[4];   // [8] f32
    float* out = (float*)d_out;                // [N,8] f32

    // workspace carve-up (512-byte aligned slices)
    char* w = (char*)d_ws;
    auto alloc = [&](size_t bytes) -> char* {
        char* p = w;
        w += (bytes + 511) & ~(size_t)511;
        return p;
    };
    uint32_t* cnt    = (uint32_t*)alloc(N_NODES * 4);
    float*    invdeg = (float*)   alloc(N_NODES * 4);
    uint32_t* perm   = (uint32_t*)alloc(N_NODES * 4);
    uint32_t* rank   = (uint32_t*)alloc(N_NODES * 4);
    uint32_t* poffs  = (uint32_t*)alloc((N_NODES + 1) * 4);
    uint32_t* pcur   = (uint32_t*)alloc(N_NODES * 4);
    uint16_t* prows  = (uint16_t*)alloc(PADCAP * 2);
    uint16_t* prows2 = (uint16_t*)alloc(PADCAP * 2);
    float*    diag   = (float*)   alloc(N_NODES * WALK_LEN * 4);

    k0_init     <<<(N_NODES + 255) / 256, 256, 0, stream>>>(cnt, invdeg);
    k1_count    <<<(N_EDGES + 255) / 256, 256, 0, stream>>>(ei, rw, cnt, invdeg);
    k2_sort     <<<1, 1024, 0, stream>>>(cnt, perm, rank);
    k3_scan     <<<1, 1024, 0, stream>>>(cnt, perm, poffs, pcur);
    k4_scatter  <<<(N_EDGES + 255) / 256, 256, 0, stream>>>(ei, rank, pcur, prows);
    k4b_banksort<<<(N_NODES + 255) / 256, 256, 0, stream>>>(cnt, perm, poffs, prows, prows2);
    k5_walk     <<<N_NODES / 4, 1024, 0, stream>>>(perm, poffs, prows2, invdeg, diag);
    k6_out      <<<(N_NODES * OUT_DIM + 255) / 256, 256, 0, stream>>>(diag, W, b, out);
}

// Round 8
// 1451.165 us; speedup vs baseline: 1.1046x; 1.1046x over previous
//
#include <hip/hip_runtime.h>
#include <stdint.h>

// ---------------- problem constants (fixed by the reference) ----------------
#define N_NODES   8000
#define N_EDGES   128000
#define WALK_LEN  16
#define OUT_DIM   8

// ---------------- main-kernel layout constants ----------------
#define WCOLS     8                    // walk columns per block (f16x8 = 16B rows)
#define NSLOT     8008                 // 8000 real rows + 8 staggered dummy zero-rows
#define PADCAP    (N_EDGES + 4 * N_NODES)  // 160000: per-col pad-to-4 worst case

typedef _Float16 half2_t __attribute__((ext_vector_type(2)));

// ---------------- K0: init cnt/invdeg ----------------
__global__ void k0_init(uint32_t* __restrict__ cnt, float* __restrict__ invdeg) {
    int i = blockIdx.x * 256 + threadIdx.x;
    if (i < N_NODES) { cnt[i] = 0u; invdeg[i] = 1.0f; }
}

// ---------------- K1: in-degree count + invdeg scatter ----------------
// invdeg[r] = rw[e] for every edge with row r (all identical: 1/deg(r)) — benign race.
// Nodes with no out-edges keep invdeg=1.0, matching the reference's clip(deg,1).
__global__ void k1_count(const int* __restrict__ ei, const float* __restrict__ rw,
                         uint32_t* __restrict__ cnt, float* __restrict__ invdeg) {
    int e = blockIdx.x * 256 + threadIdx.x;
    if (e < N_EDGES) {
        int r = ei[e];
        int c = ei[N_EDGES + e];
        atomicAdd(&cnt[c], 1u);
        invdeg[r] = rw[e];
    }
}

// ---------------- K2: counting sort of columns by in-degree ----------------
// perm[slot] = col, rank[col] = slot.  Sorted order = near-uniform trip counts per wave.
__global__ __launch_bounds__(1024) void k2_sort(const uint32_t* __restrict__ cnt,
                                                uint32_t* __restrict__ perm,
                                                uint32_t* __restrict__ rank) {
    __shared__ uint32_t h[256];
    __shared__ uint32_t hoff[256];
    int t = threadIdx.x;
    if (t < 256) h[t] = 0u;
    __syncthreads();
    for (int i = t; i < N_NODES; i += 1024) {
        uint32_t d = cnt[i]; if (d > 255u) d = 255u;
        atomicAdd(&h[d], 1u);
    }
    __syncthreads();
    if (t == 0) {
        uint32_t run = 0;
        for (int b = 0; b < 256; ++b) { hoff[b] = run; run += h[b]; }
    }
    __syncthreads();
    for (int i = t; i < N_NODES; i += 1024) {
        uint32_t d = cnt[i]; if (d > 255u) d = 255u;
        uint32_t slot = atomicAdd(&hoff[d], 1u);
        perm[slot] = (uint32_t)i;
        rank[i] = slot;
    }
}

// ---------------- K3: exclusive scan of pad-to-4 degrees over perm order ----------------
__global__ __launch_bounds__(1024) void k3_scan(const uint32_t* __restrict__ cnt,
                                                const uint32_t* __restrict__ perm,
                                                uint32_t* __restrict__ poffs,
                                                uint32_t* __restrict__ pcur) {
    __shared__ uint32_t s[2][8192];   // 64 KB, Hillis-Steele double buffer
    int t = threadIdx.x;
    for (int i = t; i < 8192; i += 1024) {
        uint32_t v = 0u;
        if (i < N_NODES) v = (cnt[perm[i]] + 3u) & ~3u;   // pad each column to x4
        s[0][i] = v;
    }
    __syncthreads();
    int src = 0;
    for (int d = 1; d < 8192; d <<= 1) {
        for (int i = t; i < 8192; i += 1024) {
            uint32_t v = s[src][i];
            if (i >= d) v += s[src][i - d];
            s[src ^ 1][i] = v;
        }
        __syncthreads();
        src ^= 1;
    }
    for (int i = t; i < 8192; i += 1024) {
        if (i < N_NODES) {
            uint32_t ex = (i == 0) ? 0u : s[src][i - 1];
            poffs[i] = ex;
            pcur[i]  = ex;
        }
    }
    if (t == 0) poffs[N_NODES] = s[src][N_NODES - 1];
}

// ---------------- K4: scatter edges into permuted CSC (plain u16 row index) ------------
__global__ void k4_scatter(const int* __restrict__ ei, const uint32_t* __restrict__ rank,
                           uint32_t* __restrict__ pcur, uint16_t* __restrict__ prows) {
    int e = blockIdx.x * 256 + threadIdx.x;
    if (e < N_EDGES) {
        int r = ei[e];
        int c = ei[N_EDGES + e];
        uint32_t slot = rank[c];
        uint32_t pos  = atomicAdd(&pcur[slot], 1u);
        prows[pos] = (uint16_t)r;
    }
}

// ---------------- K4b: per-column bank-quad stagger sort (correctness-neutral) --------
// b128 reads hit bank-quad (row & 7). Sort each column's edges by ((row&7) - rot) & 7,
// rot = lane/8 in the wave that owns this slot in k5. With degree-sorted wave-uniform
// trip counts, the wave's 64 lanes then sit at evenly staggered quads each iteration
// (8 lanes/quad = the b128 floor). Pads go to staggered dummy zero-rows 8000..8007.
__global__ __launch_bounds__(256) void k4b_banksort(const uint32_t* __restrict__ cnt,
                                                    const uint32_t* __restrict__ perm,
                                                    const uint32_t* __restrict__ poffs,
                                                    const uint16_t* __restrict__ prows,
                                                    uint16_t* __restrict__ prows2) {
    __shared__ uint16_t pos[256][8];
    int t = threadIdx.x;
    int i = blockIdx.x * 256 + t;
    if (i >= N_NODES) return;
    uint32_t col  = perm[i];
    uint32_t n    = cnt[col];
    uint32_t base = poffs[i];
    uint32_t end  = poffs[i + 1];
    uint32_t rot  = ((uint32_t)i & 63u) >> 3;   // 0..7, matches k5 lane = (i mod 1024) & 63

#pragma unroll
    for (int k = 0; k < 8; ++k) pos[t][k] = 0;
    for (uint32_t p = 0; p < n; ++p) {
        uint32_t r = (uint32_t)prows[base + p];
        pos[t][((r & 7u) + 8u - rot) & 7u]++;
    }
    uint32_t run = 0;
#pragma unroll
    for (int k = 0; k < 8; ++k) { uint32_t hh = pos[t][k]; pos[t][k] = (uint16_t)run; run += hh; }
    for (uint32_t p = 0; p < n; ++p) {
        uint16_t r = prows[base + p];
        uint32_t k = (((uint32_t)r & 7u) + 8u - rot) & 7u;
        prows2[base + pos[t][k]] = r;
        pos[t][k]++;
    }
    uint16_t dummyrow = (uint16_t)(8000u + ((rot + 7u) & 7u));  // key 7: end of sorted list
    for (uint32_t p = base + n; p < end; ++p) prows2[p] = dummyrow;
}

// ---------------- K5: the 16-step walk, 8 columns per block, reg ping-pong ------------
// State X~ = 1024 * invdeg ⊙ X in f16x8 rows (16B), SINGLE LDS buffer (128128 B).
// Per step: gather old state into f32 accs (b128 reads), hold new rows in VGPRs,
// barrier, write back, barrier.  diag_s = acc/1024 at own column.
__global__ __launch_bounds__(1024, 4) void k5_walk(const uint32_t* __restrict__ perm,
                                                   const uint32_t* __restrict__ poffs,
                                                   const uint16_t* __restrict__ prows,
                                                   const float* __restrict__ invdeg,
                                                   float* __restrict__ diag) {
    __shared__ uint4 Xs[NSLOT];   // 128128 bytes static LDS
    const int t  = threadIdx.x;
    const int c0 = blockIdx.x * WCOLS;

    // zero the buffer (dummy rows 8000..8007 stay zero forever)
    for (int i = t; i < NSLOT; i += 1024) Xs[i] = make_uint4(0u, 0u, 0u, 0u);
    __syncthreads();
    if (t < WCOLS) {
        int c = c0 + t;
        float v = invdeg[c] * 1024.0f;   // scaled one-hot, weight pre-folded
        uint32_t hw = (uint32_t)__builtin_bit_cast(uint16_t, (_Float16)v);
        uint32_t word = hw << ((t & 1) * 16);
        uint4 w = make_uint4(0u, 0u, 0u, 0u);
        int wi = t >> 1;
        if      (wi == 0) w.x = word;
        else if (wi == 1) w.y = word;
        else if (wi == 2) w.z = word;
        else              w.w = word;
        Xs[c] = w;
    }

    // cache this thread's 8 slots in registers for all 16 steps
    uint32_t sc[8], sb[8], se[8];
    float sid[8];
#pragma unroll
    for (int q = 0; q < 8; ++q) {
        int i = q * 1024 + t;
        if (i < N_NODES) {
            uint32_t c = perm[i];
            sc[q] = c;
            sb[q] = poffs[i];
            se[q] = poffs[i + 1];
            sid[q] = invdeg[c];
        } else {
            sc[q] = 0xFFFFFFFFu; sb[q] = 0u; se[q] = 0u; sid[q] = 0.0f;
        }
    }
    __syncthreads();

    const char* base = (const char*)&Xs[0];

    for (int s = 0; s < WALK_LEN; ++s) {
        uint4 pend[8];
#pragma unroll
        for (int q = 0; q < 8; ++q) {
            if (sc[q] == 0xFFFFFFFFu) { pend[q] = make_uint4(0u, 0u, 0u, 0u); continue; }
            float a0 = 0.f, a1 = 0.f, a2 = 0.f, a3 = 0.f;
            float a4 = 0.f, a5 = 0.f, a6 = 0.f, a7 = 0.f;
            for (uint32_t e = sb[q]; e < se[q]; e += 4) {
                uint2 cc = *(const uint2*)(prows + e);   // 4 u16 row indices
#define EDGE_AT(R)                                                          \
                {   uint4 wv = *(const uint4*)(base + ((uint32_t)(R) << 4));\
                    half2_t h0 = __builtin_bit_cast(half2_t, wv.x);         \
                    half2_t h1 = __builtin_bit_cast(half2_t, wv.y);         \
                    half2_t h2 = __builtin_bit_cast(half2_t, wv.z);         \
                    half2_t h3 = __builtin_bit_cast(half2_t, wv.w);         \
                    a0 += (float)h0.x;  a1 += (float)h0.y;                  \
                    a2 += (float)h1.x;  a3 += (float)h1.y;                  \
                    a4 += (float)h2.x;  a5 += (float)h2.y;                  \
                    a6 += (float)h3.x;  a7 += (float)h3.y;                  \
                }
                EDGE_AT(cc.x & 0xFFFFu)  EDGE_AT(cc.x >> 16)
                EDGE_AT(cc.y & 0xFFFFu)  EDGE_AT(cc.y >> 16)
#undef EDGE_AT
            }
            uint32_t c = sc[q];
            uint32_t j = c - (uint32_t)c0;
            if (j < 8u) {   // this column's diagonal entry (undo the x1024 scaling)
                float dv = a0;
                dv = (j == 1u) ? a1 : dv;
                dv = (j == 2u) ? a2 : dv;
                dv = (j == 3u) ? a3 : dv;
                dv = (j == 4u) ? a4 : dv;
                dv = (j == 5u) ? a5 : dv;
                dv = (j == 6u) ? a6 : dv;
                dv = (j == 7u) ? a7 : dv;
                diag[c * WALK_LEN + s] = dv * (1.0f / 1024.0f);
            }
            float id = sid[q];
            half2_t h01, h23, h45, h67;
            h01.x = (_Float16)(a0 * id);  h01.y = (_Float16)(a1 * id);
            h23.x = (_Float16)(a2 * id);  h23.y = (_Float16)(a3 * id);
            h45.x = (_Float16)(a4 * id);  h45.y = (_Float16)(a5 * id);
            h67.x = (_Float16)(a6 * id);  h67.y = (_Float16)(a7 * id);
            pend[q].x = __builtin_bit_cast(uint32_t, h01);
            pend[q].y = __builtin_bit_cast(uint32_t, h23);
            pend[q].z = __builtin_bit_cast(uint32_t, h45);
            pend[q].w = __builtin_bit_cast(uint32_t, h67);
        }
        __syncthreads();   // all reads of old state done
#pragma unroll
        for (int q = 0; q < 8; ++q)
            if (sc[q] != 0xFFFFFFFFu) Xs[sc[q]] = pend[q];
        __syncthreads();   // new state visible
    }
}

// ---------------- K6: linear layer out = diag @ W^T + b ----------------
__global__ void k6_out(const float* __restrict__ diag, const float* __restrict__ W,
                       const float* __restrict__ b, float* __restrict__ out) {
    int i = blockIdx.x * 256 + threadIdx.x;
    if (i < N_NODES * OUT_DIM) {
        int n = i >> 3;
        int d = i & 7;
        float acc = b[d];
#pragma unroll
        for (int k = 0; k < WALK_LEN; ++k)
            acc += diag[n * WALK_LEN + k] * W[d * WALK_LEN + k];
        out[i] = acc;
    }
}

// ---------------- launcher ----------------
extern "C" void kernel_launch(void* const* d_in, const int* in_sizes, int n_in,
                              void* d_out, int out_size, void* d_ws, size_t ws_size,
                              hipStream_t stream) {
    const int*   ei = (const int*)d_in[0];     // [2, E] int32: rows then cols
    const float* rw = (const float*)d_in[2];   // [E] f32
    const float* W  = (const float*)d_in[3];   // [8,16] f32
    const float* b  = (const float*)d_in[4];   // [8] f32
    float* out = (float*)d_out;                // [N,8] f32

    // workspace carve-up (512-byte aligned slices)
    char* w = (char*)d_ws;
    auto alloc = [&](size_t bytes) -> char* {
        char* p = w;
        w += (bytes + 511) & ~(size_t)511;
        return p;
    };
    uint32_t* cnt    = (uint32_t*)alloc(N_NODES * 4);
    float*    invdeg = (float*)   alloc(N_NODES * 4);
    uint32_t* perm   = (uint32_t*)alloc(N_NODES * 4);
    uint32_t* rank   = (uint32_t*)alloc(N_NODES * 4);
    uint32_t* poffs  = (uint32_t*)alloc((N_NODES + 1) * 4);
    uint32_t* pcur   = (uint32_t*)alloc(N_NODES * 4);
    uint16_t* prows  = (uint16_t*)alloc(PADCAP * 2);
    uint16_t* prows2 = (uint16_t*)alloc(PADCAP * 2);
    float*    diag   = (float*)   alloc(N_NODES * WALK_LEN * 4);

    k0_init     <<<(N_NODES + 255) / 256, 256, 0, stream>>>(cnt, invdeg);
    k1_count    <<<(N_EDGES + 255) / 256, 256, 0, stream>>>(ei, rw, cnt, invdeg);
    k2_sort     <<<1, 1024, 0, stream>>>(cnt, perm, rank);
    k3_scan     <<<1, 1024, 0, stream>>>(cnt, perm, poffs, pcur);
    k4_scatter  <<<(N_EDGES + 255) / 256, 256, 0, stream>>>(ei, rank, pcur, prows);
    k4b_banksort<<<(N_NODES + 255) / 256, 256, 0, stream>>>(cnt, perm, poffs, prows, prows2);
    k5_walk     <<<N_NODES / WCOLS, 1024, 0, stream>>>(perm, poffs, prows2, invdeg, diag);
    k6_out      <<<(N_NODES * OUT_DIM + 255) / 256, 256, 0, stream>>>(diag, W, b, out);
}